// Round 23
// baseline (378.779 us; speedup 1.0000x reference)
//
#include <hip/hip_runtime.h>
#include <math.h>

#define SEQ 2048
#define HID 3584
#define NH 28
#define NKV 4
#define HD 128
#define GQA (NH / NKV)
#define NQKV (NH * HD + 2 * NKV * HD)  // 4608
#define NSLOT 34                       // rebalanced slots/head, max 10 tiles/chunk
#define KS2 0.12752997f                // (1/sqrt(128)) * log2(e)
#define DTHR 90.50967f                 // 8 / (1/sqrt(128)) : defer-max threshold (raw domain)

typedef __attribute__((ext_vector_type(8))) short short8;
typedef __attribute__((ext_vector_type(4))) float f32x4;
typedef __attribute__((ext_vector_type(16))) float f32x16;
typedef unsigned int u32;
typedef unsigned short ushort_t;

// slot tables (dispatch order = longest chunk first within each XCD stream)
__device__ __constant__ unsigned char SLOT_QT[NSLOT] = {
    14,14,14, 9, 9, 4,13,13,13,12,12, 8, 8,15,15,15,15,
    12,11,11,11,10, 7, 7, 3,10,10, 6, 6, 5, 5, 2, 1, 0};
__device__ __constant__ unsigned char SLOT_C[NSLOT] = {
    0, 1, 2, 0, 1, 0, 2, 0, 1, 1, 2, 0, 1, 0, 1, 2, 3,
    0, 0, 1, 2, 2, 0, 1, 0, 0, 1, 0, 1, 0, 1, 0, 0, 0};
__device__ __constant__ unsigned char QT_NC[16] = {1,1,1,1,1,2,2,2,2,2,3,3,3,3,3,4};
__device__ __constant__ unsigned char RED_BASE[16] = {0,1,2,3,4,5,7,9,11,13,15,18,21,24,27,30};
__device__ __constant__ unsigned char RED_SLOT[NSLOT] = {
    33,32,31,24, 5,29,30,27,28,22,23,11,12, 3, 4,
    25,26,21,18,19,20,17, 9,10, 7, 8, 6, 0, 1, 2,13,14,15,16};

__device__ inline ushort_t f2bf(float f) {
  u32 x = __float_as_uint(f);
  return (ushort_t)((x + 0x7FFFu + ((x >> 16) & 1u)) >> 16);
}
__device__ inline float bf2f(ushort_t h) {
  return __uint_as_float(((u32)h) << 16);
}
__device__ inline u32 cvtpk(float lo, float hi) {  // bf16(lo) | bf16(hi)<<16, HW RNE
  u32 r;
  asm("v_cvt_pk_bf16_f32 %0, %1, %2" : "=v"(r) : "v"(lo), "v"(hi));
  return r;
}
__device__ inline void gload16(const void* g, void* l) {
  __builtin_amdgcn_global_load_lds((const u32 __attribute__((address_space(1)))*)g,
                                   (u32 __attribute__((address_space(3)))*)l, 16, 0, 0);
}

// ---------------- cast x -> bf16 ----------------
__global__ __launch_bounds__(256) void cast_bf16_kernel(const float* __restrict__ in,
                                                        ushort_t* __restrict__ out, int n4) {
  int i = blockIdx.x * blockDim.x + threadIdx.x;
  if (i >= n4) return;
  float4 v = ((const float4*)in)[i];
  ushort4 o;
  o.x = f2bf(v.x); o.y = f2bf(v.y); o.z = f2bf(v.z); o.w = f2bf(v.w);
  *(ushort4*)&out[(size_t)i * 4] = o;
}

// ---------------- transpose-cast: in [K][N] f32 -> out [N][K] bf16 ----------------
__global__ __launch_bounds__(256) void transpose_cast_kernel(const float* __restrict__ in,
                                                             ushort_t* __restrict__ out,
                                                             int K, int N) {
  __shared__ ushort_t t[64][65];
  const int bk = blockIdx.y * 64, bn = blockIdx.x * 64;
  const int tid = threadIdx.x;
#pragma unroll
  for (int i = 0; i < 4; i++) {
    int idx = i * 256 + tid;
    int r = idx >> 4, c4 = idx & 15;
    float4 v = *(const float4*)&in[(size_t)(bk + r) * N + bn + c4 * 4];
    t[c4 * 4 + 0][r] = f2bf(v.x);
    t[c4 * 4 + 1][r] = f2bf(v.y);
    t[c4 * 4 + 2][r] = f2bf(v.z);
    t[c4 * 4 + 3][r] = f2bf(v.w);
  }
  __syncthreads();
#pragma unroll
  for (int i = 0; i < 4; i++) {
    int idx = i * 256 + tid;
    int r = idx >> 4, c4 = idx & 15;
    ushort4 o;
    o.x = t[r][c4 * 4 + 0]; o.y = t[r][c4 * 4 + 1];
    o.z = t[r][c4 * 4 + 2]; o.w = t[r][c4 * 4 + 3];
    *(ushort4*)&out[(size_t)(bn + r) * K + bk + c4 * 4] = o;
  }
}

// ---------------- fused QKV weight transpose-cast into wT[4608][3584] ----------------
__global__ __launch_bounds__(256) void transpose_cast_qkv(
    const float* __restrict__ wq, const float* __restrict__ wk,
    const float* __restrict__ wv, ushort_t* __restrict__ out) {
  __shared__ ushort_t t[64][65];
  const int xb = blockIdx.x;           // n-tile in fused [0,72)
  const int bk = blockIdx.y * 64;
  const int tid = threadIdx.x;
  const float* src; int srcN, bnl;
  if (xb < 56) { src = wq; srcN = NH * HD; bnl = xb * 64; }
  else if (xb < 64) { src = wk; srcN = NKV * HD; bnl = (xb - 56) * 64; }
  else { src = wv; srcN = NKV * HD; bnl = (xb - 64) * 64; }
#pragma unroll
  for (int i = 0; i < 4; i++) {
    int idx = i * 256 + tid;
    int r = idx >> 4, c4 = idx & 15;
    float4 v = *(const float4*)&src[(size_t)(bk + r) * srcN + bnl + c4 * 4];
    t[c4 * 4 + 0][r] = f2bf(v.x);
    t[c4 * 4 + 1][r] = f2bf(v.y);
    t[c4 * 4 + 2][r] = f2bf(v.z);
    t[c4 * 4 + 3][r] = f2bf(v.w);
  }
  __syncthreads();
#pragma unroll
  for (int i = 0; i < 4; i++) {
    int idx = i * 256 + tid;
    int r = idx >> 4, c4 = idx & 15;
    ushort4 o;
    o.x = t[r][c4 * 4 + 0]; o.y = t[r][c4 * 4 + 1];
    o.z = t[r][c4 * 4 + 2]; o.w = t[r][c4 * 4 + 3];
    *(ushort4*)&out[(size_t)(xb * 64 + r) * HID + bk + c4 * 4] = o;
  }
}

// ---------------- bf16 MFMA GEMM: 128x64 tile, BK=32, 4 waves ----------------
// Same winning per-wave acc[2][4] micro-tile; finer tiles give 1152/896-block
// grids (4.5/3.5 blocks/CU): quantization tail 33% -> 11%. LDS 24 KB dbuf.
__global__ __launch_bounds__(256) void gemm_mfma(
    const ushort_t* __restrict__ A, const ushort_t* __restrict__ BT,
    const float* __restrict__ bias, float* __restrict__ Cf, ushort_t* __restrict__ Cb,
    ushort_t* __restrict__ Ck, ushort_t* __restrict__ Cv,
    const float* __restrict__ bias_k, const float* __restrict__ bias_v,
    int M, int N, int K, int mode) {
  __shared__ __align__(16) ushort_t As[2][128 * 32];  // 16 KB
  __shared__ __align__(16) ushort_t Bs[2][64 * 32];   // 8 KB
  const int tid = threadIdx.x;
  const int w = tid >> 6, lane = tid & 63;
  const int g = lane >> 4, r16 = lane & 15;
  const int wr = w;                     // 4 x 1 wave grid; wave tile 32x64
  const int swzr = (r16 >> 1) & 3;      // fragment-read granule swizzle

  // XCD-chunked bijective swizzle (m204): B-panel resident per XCD L2
  const int nwg = gridDim.x;
  const int ny = M >> 7;
  const int qq = nwg >> 3, rr = nwg & 7;
  const int xcd = blockIdx.x & 7, jj = blockIdx.x >> 3;
  const int wgid = (xcd < rr ? xcd * (qq + 1) : rr * (qq + 1) + (xcd - rr) * qq) + jj;
  const int bn = (wgid / ny) * 64;
  const int bm = (wgid % ny) * 128;

  f32x4 acc[2][4];
#pragma unroll
  for (int i = 0; i < 2; i++)
#pragma unroll
    for (int j2 = 0; j2 < 4; j2++) acc[i][j2] = (f32x4){0.f, 0.f, 0.f, 0.f};

  const int nk = K >> 5;  // 112

  // stage A 128x32 (512 granules: 2/thread) + B 64x32 (256: 1/thread)
#define GSTAGE(BUF, T_)                                                                 \
  do {                                                                                  \
    const int k0_ = (T_) << 5;                                                          \
    _Pragma("unroll") for (int i2 = 0; i2 < 2; i2++) {                                  \
      int gi = i2 * 256 + tid;                                                          \
      int row = gi >> 2, gc = gi & 3;                                                   \
      int gsrc = gc ^ ((row >> 1) & 3);                                                 \
      gload16(&A[(size_t)(bm + row) * K + k0_ + gsrc * 8], &As[BUF][gi * 8]);           \
    }                                                                                   \
    {                                                                                   \
      int gi = tid;                                                                     \
      int row = gi >> 2, gc = gi & 3;                                                   \
      int gsrc = gc ^ ((row >> 1) & 3);                                                 \
      gload16(&BT[(size_t)(bn + row) * K + k0_ + gsrc * 8], &Bs[BUF][gi * 8]);          \
    }                                                                                   \
  } while (0)

  GSTAGE(0, 0);
  __syncthreads();

  int buf = 0;
  for (int t = 0; t < nk; t++) {
    if (t + 1 < nk) GSTAGE(buf ^ 1, t + 1);
    short8 af[2], bfr[4];
#pragma unroll
    for (int mi = 0; mi < 2; mi++)
      af[mi] = *(const short8*)&As[buf][((wr * 32 + mi * 16 + r16) * 4 + (g ^ swzr)) * 8];
#pragma unroll
    for (int ni = 0; ni < 4; ni++)
      bfr[ni] = *(const short8*)&Bs[buf][((ni * 16 + r16) * 4 + (g ^ swzr)) * 8];
    __builtin_amdgcn_s_setprio(1);
#pragma unroll
    for (int mi = 0; mi < 2; mi++)
#pragma unroll
      for (int ni = 0; ni < 4; ni++)
        acc[mi][ni] = __builtin_amdgcn_mfma_f32_16x16x32_bf16(af[mi], bfr[ni], acc[mi][ni], 0, 0, 0);
    __builtin_amdgcn_s_setprio(0);
    __syncthreads();
    buf ^= 1;
  }
#undef GSTAGE

  if (mode == 3) {
#pragma unroll
    for (int mi = 0; mi < 2; mi++)
#pragma unroll
      for (int ni = 0; ni < 4; ni++)
#pragma unroll
        for (int r = 0; r < 4; r++) {
          int row = bm + wr * 32 + mi * 16 + 4 * g + r;
          int col = bn + ni * 16 + r16;
          float v = acc[mi][ni][r];
          if (bn < NH * HD) {
            Cb[(size_t)row * (NH * HD) + col] = f2bf(v + bias[col]);
          } else if (bn < NH * HD + NKV * HD) {
            int c = col - NH * HD;
            Ck[(size_t)row * (NKV * HD) + c] = f2bf(v + bias_k[c]);
          } else {
            int c = col - (NH * HD + NKV * HD);
            Cv[(size_t)c * M + row] = f2bf(v + bias_v[c]);
          }
        }
    return;
  }
#pragma unroll
  for (int mi = 0; mi < 2; mi++)
#pragma unroll
    for (int ni = 0; ni < 4; ni++)
#pragma unroll
      for (int r = 0; r < 4; r++) {
        int row = bm + wr * 32 + mi * 16 + 4 * g + r;
        int col = bn + ni * 16 + r16;
        float v = acc[mi][ni][r];
        if (bias) v += bias[col];
        if (mode == 0) Cf[(size_t)row * N + col] = v;
        else Cb[(size_t)row * N + col] = f2bf(v);
      }
}

// ---------------- fused RoPE on q[S][NH][128] + k[S][NKV][128] (bf16, vectorized) ----
__global__ __launch_bounds__(256) void rope_fused(
    ushort_t* __restrict__ q, ushort_t* __restrict__ k,
    const float* __restrict__ cosd, const float* __restrict__ sind) {
  const int s = blockIdx.x;
  const int t = threadIdx.x;
  const int hg = t >> 3;        // 0..31: 0-27 q heads, 28-31 k heads
  const int d0 = (t & 7) * 8;   // 0..56
  ushort_t* p = (hg < NH) ? q + ((size_t)s * NH + hg) * HD
                          : k + ((size_t)s * NKV + (hg - NH)) * HD;
  short8 a = *(short8*)(p + d0);
  short8 b = *(short8*)(p + d0 + 64);
  float4 c0 = *(const float4*)&cosd[s * 64 + d0];
  float4 c1 = *(const float4*)&cosd[s * 64 + d0 + 4];
  float4 s0 = *(const float4*)&sind[s * 64 + d0];
  float4 s1 = *(const float4*)&sind[s * 64 + d0 + 4];
  float cs[8] = {c0.x, c0.y, c0.z, c0.w, c1.x, c1.y, c1.z, c1.w};
  float sn[8] = {s0.x, s0.y, s0.z, s0.w, s1.x, s1.y, s1.z, s1.w};
  short8 ra, rb;
#pragma unroll
  for (int j = 0; j < 8; j++) {
    float x1 = bf2f((ushort_t)a[j]), x2 = bf2f((ushort_t)b[j]);
    ra[j] = (short)f2bf(x1 * cs[j] - x2 * sn[j]);
    rb[j] = (short)f2bf(x1 * sn[j] + x2 * cs[j]);
  }
  *(short8*)(p + d0) = ra;
  *(short8*)(p + d0 + 64) = rb;
}

// ---------------- split-K 32x32 swapped-operand causal GQA flash attention ----
// 1D grid 952; xcd = id&7; each XCD pair owns one kv-head (K+V = 4MB fits
// per-XCD L2). K AND V staged in LDS (dbuf, granule swizzle) - best measured.
// P packed with HW v_cvt_pk_bf16_f32; 4-chain max reduce.
__global__ __launch_bounds__(256) void attn_split(
    const ushort_t* __restrict__ q, const ushort_t* __restrict__ k,
    const ushort_t* __restrict__ vT, ushort_t* __restrict__ Opart,
    float* __restrict__ Mpart, float* __restrict__ Lpart) {
  const int i = blockIdx.x;          // 0..951
  const int xcd = i & 7, idx = i >> 3;
  const int kvh_ = xcd >> 1;
  const int j = idx * 2 + (xcd & 1); // 0..237 = 7 heads x 34 slots
  const int h = kvh_ * 7 + j / NSLOT;
  const int slotIdx = j % NSLOT;
  const int qt = SLOT_QT[slotIdx];
  const int c = SLOT_C[slotIdx], C = QT_NC[qt];
  const int T = 2 * qt + 2;
  const int tstart = (T * c) / C;
  const int tend = (T * (c + 1)) / C;
  const size_t slot = (size_t)h * NSLOT + slotIdx;
  const int kvh = h / GQA;
  const int q0 = qt * 128;
  const int tid = threadIdx.x, w = tid >> 6, lane = tid & 63;
  const int l31 = lane & 31, hi = lane >> 5;

  __shared__ __align__(16) ushort_t Ks[2][64 * 128];  // [key][d], granule ^= key&15
  __shared__ __align__(16) ushort_t Vs[2][128 * 64];  // [d][key], granule ^= d&7

  short8 qf[8];
  {
    const ushort_t* qp = q + (size_t)(q0 + w * 32 + l31) * (NH * HD) + h * HD + 8 * hi;
#pragma unroll
    for (int f = 0; f < 8; f++) qf[f] = *(const short8*)(qp + 16 * f);
  }
  float mrow = -1e30f, lrow = 0.f;
  f32x16 oa[4];
#pragma unroll
  for (int d = 0; d < 4; d++)
#pragma unroll
    for (int e = 0; e < 16; e++) oa[d][e] = 0.f;

#define STAGE(BUF, T_)                                                                  \
  do {                                                                                  \
    const int kb_ = (T_) * 64;                                                          \
    _Pragma("unroll") for (int i2 = 0; i2 < 4; i2++) {                                  \
      int gi = i2 * 256 + tid;                                                          \
      int key = gi >> 4, gd = gi & 15;                                                  \
      int gsrc = gd ^ (key & 15);                                                       \
      gload16(&k[(size_t)(kb_ + key) * (NKV * HD) + kvh * HD + gsrc * 8],               \
              &Ks[BUF][gi * 8]);                                                        \
    }                                                                                   \
    _Pragma("unroll") for (int i2 = 0; i2 < 4; i2++) {                                  \
      int gi = i2 * 256 + tid;                                                          \
      int drow = gi >> 3, gc = gi & 7;                                                  \
      int gsrc = gc ^ (drow & 7);                                                       \
      gload16(&vT[(size_t)(kvh * HD + drow) * SEQ + kb_ + gsrc * 8],                    \
              &Vs[BUF][gi * 8]);                                                        \
    }                                                                                   \
  } while (0)

  STAGE(0, tstart);
  __syncthreads();

  for (int t = tstart; t < tend; t++) {
    const int cur = (t - tstart) & 1;
    const int kb = t * 64;
    if (t + 1 < tend) STAGE(cur ^ 1, t + 1);

    const int qwave = q0 + w * 32;
    if (kb <= qwave + 31) {
      // ---- QK^T ----
      f32x16 sfr[2];
      __builtin_amdgcn_s_setprio(1);
#pragma unroll
      for (int st = 0; st < 2; st++) {
        f32x16 acc;
#pragma unroll
        for (int e = 0; e < 16; e++) acc[e] = 0.f;
        const int key = st * 32 + l31;
#pragma unroll
        for (int f = 0; f < 8; f++) {
          short8 kf = *(const short8*)&Ks[cur][(key * 16 + ((2 * f + hi) ^ (key & 15))) * 8];
          acc = __builtin_amdgcn_mfma_f32_32x32x16_bf16(kf, qf[f], acc, 0, 0, 0);
        }
        sfr[st] = acc;
      }
      __builtin_amdgcn_s_setprio(0);

      // ---- causal mask ----
      const int qg = q0 + w * 32 + l31;
      if (kb + 63 > qwave) {
#pragma unroll
        for (int st = 0; st < 2; st++)
#pragma unroll
          for (int e = 0; e < 16; e++) {
            int keyg = kb + st * 32 + (e & 3) + 8 * (e >> 2) + 4 * hi;
            if (keyg > qg) sfr[st][e] = -1e30f;
          }
      }

      // ---- per-lane online softmax (defer-max); 4-chain max reduce ----
      float pmv0 = -1e30f, pmv1 = -1e30f, pmv2 = -1e30f, pmv3 = -1e30f;
#pragma unroll
      for (int st = 0; st < 2; st++)
#pragma unroll
        for (int e = 0; e < 16; e += 4) {
          pmv0 = fmaxf(pmv0, sfr[st][e]);
          pmv1 = fmaxf(pmv1, sfr[st][e + 1]);
          pmv2 = fmaxf(pmv2, sfr[st][e + 2]);
          pmv3 = fmaxf(pmv3, sfr[st][e + 3]);
        }
      float pm = fmaxf(fmaxf(pmv0, pmv1), fmaxf(pmv2, pmv3));
      if (__any(pm > mrow + DTHR)) {
        float xm = fmaxf(pm, __shfl_xor(pm, 32));
        float nm = fmaxf(mrow, xm);
        float resc = exp2f((mrow - nm) * KS2);
        mrow = nm;
        lrow *= resc;
        float rr2[16];
#pragma unroll
        for (int r = 0; r < 16; r++) {
          int srcl = (r & 3) + 8 * (r >> 2) + 4 * hi;
          rr2[r] = __shfl(resc, srcl);
        }
#pragma unroll
        for (int d = 0; d < 4; d++)
#pragma unroll
          for (int r = 0; r < 16; r++) oa[d][r] *= rr2[r];
      }
      u32 pk[2][8];
      float psum = 0.f;
#pragma unroll
      for (int st = 0; st < 2; st++)
#pragma unroll
        for (int j2 = 0; j2 < 8; j2++) {
          float pa = exp2f((sfr[st][2 * j2] - mrow) * KS2);
          float pb = exp2f((sfr[st][2 * j2 + 1] - mrow) * KS2);
          psum += pa + pb;
          pk[st][j2] = cvtpk(pa, pb);
        }
      lrow += psum;

      // ---- build P A-frags via shfl_xor(32) ----
      short8 paf[4];
#pragma unroll
      for (int st = 0; st < 2; st++) {
        u32 x0 = (u32)__shfl_xor((int)pk[st][0], 32);
        u32 x1 = (u32)__shfl_xor((int)pk[st][1], 32);
        u32 x2 = (u32)__shfl_xor((int)pk[st][2], 32);
        u32 x3 = (u32)__shfl_xor((int)pk[st][3], 32);
        u32 x4 = (u32)__shfl_xor((int)pk[st][4], 32);
        u32 x5 = (u32)__shfl_xor((int)pk[st][5], 32);
        u32 x6 = (u32)__shfl_xor((int)pk[st][6], 32);
        u32 x7 = (u32)__shfl_xor((int)pk[st][7], 32);
        union { u32 wd[4]; short8 v; } fe, fo;
        if (hi == 0) {
          fe.wd[0] = pk[st][0]; fe.wd[1] = pk[st][1]; fe.wd[2] = x0; fe.wd[3] = x1;
          fo.wd[0] = pk[st][4]; fo.wd[1] = pk[st][5]; fo.wd[2] = x4; fo.wd[3] = x5;
        } else {
          fe.wd[0] = x2; fe.wd[1] = x3; fe.wd[2] = pk[st][2]; fe.wd[3] = pk[st][3];
          fo.wd[0] = x6; fo.wd[1] = x7; fo.wd[2] = pk[st][6]; fo.wd[3] = pk[st][7];
        }
        paf[2 * st] = fe.v;
        paf[2 * st + 1] = fo.v;
      }

      // ---- PV from LDS V (granule-swizzled) ----
#pragma unroll
      for (int half = 0; half < 2; half++) {
        short8 vf[8];
#pragma unroll
        for (int db = 0; db < 2; db++)
#pragma unroll
          for (int ks = 0; ks < 4; ks++) {
            int drow = (half * 2 + db) * 32 + l31;
            vf[db * 4 + ks] =
                *(const short8*)&Vs[cur][(drow * 8 + ((ks * 2 + hi) ^ (drow & 7))) * 8];
          }
        __builtin_amdgcn_s_setprio(1);
#pragma unroll
        for (int db = 0; db < 2; db++)
#pragma unroll
          for (int ks = 0; ks < 4; ks++)
            oa[half * 2 + db] = __builtin_amdgcn_mfma_f32_32x32x16_bf16(
                paf[ks], vf[db * 4 + ks], oa[half * 2 + db], 0, 0, 0);
        __builtin_amdgcn_s_setprio(0);
      }
    }
    __syncthreads();
  }
#undef STAGE

  // ---- epilogue ----
  lrow += __shfl_xor(lrow, 32);
#pragma unroll
  for (int d = 0; d < 4; d++)
#pragma unroll
    for (int r = 0; r < 16; r++) {
      int qloc = w * 32 + (r & 3) + 8 * (r >> 2) + 4 * hi;
      Opart[(slot * 128 + qloc) * 128 + d * 32 + l31] = f2bf(oa[d][r]);
    }
  if (hi == 0) {
    Mpart[slot * 128 + w * 32 + l31] = mrow;
    Lpart[slot * 128 + w * 32 + l31] = lrow;
  }
}

// ---------------- combine split-K partials (vectorized: ushort4, 2 units/thread) ----
__global__ __launch_bounds__(448) void attn_reduce(
    const ushort_t* __restrict__ Opart, const float* __restrict__ Mpart,
    const float* __restrict__ Lpart, ushort_t* __restrict__ out) {
  const int s = blockIdx.x;
  const int qt = s >> 7, lr = s & 127;
  const int C = QT_NC[qt];
#pragma unroll
  for (int u = threadIdx.x; u < 896; u += 448) {
    const int h = u >> 5;         // 0..27
    const int d4 = (u & 31) * 4;  // 0..124
    float Mv[4];
    float M = -1e30f;
    for (int c = 0; c < C; c++) {
      int sl = RED_SLOT[RED_BASE[qt] + c];
      Mv[c] = Mpart[((size_t)h * NSLOT + sl) * 128 + lr];
      M = fmaxf(M, Mv[c]);
    }
    float L = 0.f, O0 = 0.f, O1 = 0.f, O2 = 0.f, O3 = 0.f;
    for (int c = 0; c < C; c++) {
      int sl = RED_SLOT[RED_BASE[qt] + c];
      size_t base = ((size_t)h * NSLOT + sl) * 128 + lr;
      float wgt = exp2f((Mv[c] - M) * KS2);
      L += wgt * Lpart[base];
      ushort4 o4 = *(const ushort4*)&Opart[base * 128 + d4];
      O0 += wgt * bf2f(o4.x); O1 += wgt * bf2f(o4.y);
      O2 += wgt * bf2f(o4.z); O3 += wgt * bf2f(o4.w);
    }
    const float inv = 1.f / L;
    ushort4 r;
    r.x = f2bf(O0 * inv); r.y = f2bf(O1 * inv);
    r.z = f2bf(O2 * inv); r.w = f2bf(O3 * inv);
    *(ushort4*)&out[(size_t)s * (NH * HD) + h * HD + d4] = r;
  }
}

extern "C" void kernel_launch(void* const* d_in, const int* in_sizes, int n_in,
                              void* d_out, int out_size, void* d_ws, size_t ws_size,
                              hipStream_t stream) {
  const float* x    = (const float*)d_in[0];
  const float* wq   = (const float*)d_in[1];
  const float* bq   = (const float*)d_in[2];
  const float* wk   = (const float*)d_in[3];
  const float* bk   = (const float*)d_in[4];
  const float* wv   = (const float*)d_in[5];
  const float* bv   = (const float*)d_in[6];
  const float* wo   = (const float*)d_in[7];
  const float* cosd = (const float*)d_in[8];
  const float* sind = (const float*)d_in[9];
  float* out = (float*)d_out;

  ushort_t* ws   = (ushort_t*)d_ws;
  ushort_t* wT   = ws;                              // [4608][3584] qkv^T; later partials; later wo^T
  ushort_t* xb   = wT + (size_t)NQKV * HID;         // [2048][3584] (later attn out)
  ushort_t* qb   = xb + (size_t)SEQ * HID;          // [2048][3584]
  ushort_t* kb_  = qb + (size_t)SEQ * HID;          // [2048][512]
  ushort_t* vbT  = kb_ + (size_t)SEQ * (NKV * HD);  // [512][2048]
  ushort_t* aob  = xb;                              // reuse after QKV GEMM

  // split-K partials overlay the (dead after QKV GEMM) wT region:
  // 28*34*128*128*2B = 31.2MB + 2*28*34*128*4B = 0.98MB <= 33.0MB
  ushort_t* Opart = wT;                                            // [28][34][128][128] bf16
  float* Mpart = (float*)(wT + (size_t)NH * NSLOT * 128 * 128);    // [28][34][128]
  float* Lpart = Mpart + (size_t)NH * NSLOT * 128;                 // [28][34][128]

  // 1. cast x -> bf16
  cast_bf16_kernel<<<(SEQ * HID / 4) / 256, 256, 0, stream>>>(x, xb, SEQ * HID / 4);
  // 2. fused transpose-cast of wq/wk/wv into [4608][3584]
  transpose_cast_qkv<<<dim3(NQKV / 64, HID / 64), 256, 0, stream>>>(wq, wk, wv, wT);
  // 3. fused QKV projection (128x64 tiles, 4 waves, 1D grid, XCD-chunked)
  gemm_mfma<<<dim3((NQKV / 64) * (SEQ / 128)), 256, 0, stream>>>(
      xb, wT, bq, nullptr, qb, kb_, vbT, bk, bv, SEQ, NQKV, HID, 3);
  // 4. fused RoPE on q and k (vectorized)
  rope_fused<<<dim3(SEQ), 256, 0, stream>>>(qb, kb_, cosd, sind);
  // 5. split-K attention (XCD-pinned 1D grid) + reduce
  attn_split<<<dim3(8 * 119), 256, 0, stream>>>(qb, kb_, vbT, Opart, Mpart, Lpart);
  attn_reduce<<<dim3(SEQ), 448, 0, stream>>>(Opart, Mpart, Lpart, aob);
  // 6. output projection (reuse wT region for wo^T; partials dead after reduce)
  transpose_cast_kernel<<<dim3(HID / 64, HID / 64), 256, 0, stream>>>(wo, wT, HID, HID);
  gemm_mfma<<<dim3((HID / 64) * (SEQ / 128)), 256, 0, stream>>>(
      aob, wT, nullptr, out, nullptr, nullptr, nullptr, nullptr, nullptr, SEQ, HID, HID, 0);
}

// Round 24
// 319.698 us; speedup vs baseline: 1.1848x; 1.1848x over previous
//
#include <hip/hip_runtime.h>
#include <math.h>

#define SEQ 2048
#define HID 3584
#define NH 28
#define NKV 4
#define HD 128
#define GQA (NH / NKV)
#define NQKV (NH * HD + 2 * NKV * HD)  // 4608
#define NSLOT 34                       // rebalanced slots/head, max 10 tiles/chunk
#define KS2 0.12752997f                // (1/sqrt(128)) * log2(e)
#define DTHR 90.50967f                 // 8 / (1/sqrt(128)) : defer-max threshold (raw domain)

typedef __attribute__((ext_vector_type(8))) short short8;
typedef __attribute__((ext_vector_type(4))) float f32x4;
typedef __attribute__((ext_vector_type(16))) float f32x16;
typedef unsigned int u32;
typedef unsigned short ushort_t;

// slot tables (dispatch order = longest chunk first within each XCD stream)
__device__ __constant__ unsigned char SLOT_QT[NSLOT] = {
    14,14,14, 9, 9, 4,13,13,13,12,12, 8, 8,15,15,15,15,
    12,11,11,11,10, 7, 7, 3,10,10, 6, 6, 5, 5, 2, 1, 0};
__device__ __constant__ unsigned char SLOT_C[NSLOT] = {
    0, 1, 2, 0, 1, 0, 2, 0, 1, 1, 2, 0, 1, 0, 1, 2, 3,
    0, 0, 1, 2, 2, 0, 1, 0, 0, 1, 0, 1, 0, 1, 0, 0, 0};
__device__ __constant__ unsigned char QT_NC[16] = {1,1,1,1,1,2,2,2,2,2,3,3,3,3,3,4};
__device__ __constant__ unsigned char RED_BASE[16] = {0,1,2,3,4,5,7,9,11,13,15,18,21,24,27,30};
__device__ __constant__ unsigned char RED_SLOT[NSLOT] = {
    33,32,31,24, 5,29,30,27,28,22,23,11,12, 3, 4,
    25,26,21,18,19,20,17, 9,10, 7, 8, 6, 0, 1, 2,13,14,15,16};

__device__ inline ushort_t f2bf(float f) {
  u32 x = __float_as_uint(f);
  return (ushort_t)((x + 0x7FFFu + ((x >> 16) & 1u)) >> 16);
}
__device__ inline float bf2f(ushort_t h) {
  return __uint_as_float(((u32)h) << 16);
}
__device__ inline u32 cvtpk(float lo, float hi) {  // bf16(lo) | bf16(hi)<<16, HW RNE
  u32 r;
  asm("v_cvt_pk_bf16_f32 %0, %1, %2" : "=v"(r) : "v"(lo), "v"(hi));
  return r;
}
__device__ inline void gload16(const void* g, void* l) {
  __builtin_amdgcn_global_load_lds((const u32 __attribute__((address_space(1)))*)g,
                                   (u32 __attribute__((address_space(3)))*)l, 16, 0, 0);
}

// ---------------- cast x -> bf16 ----------------
__global__ __launch_bounds__(256) void cast_bf16_kernel(const float* __restrict__ in,
                                                        ushort_t* __restrict__ out, int n4) {
  int i = blockIdx.x * blockDim.x + threadIdx.x;
  if (i >= n4) return;
  float4 v = ((const float4*)in)[i];
  ushort4 o;
  o.x = f2bf(v.x); o.y = f2bf(v.y); o.z = f2bf(v.z); o.w = f2bf(v.w);
  *(ushort4*)&out[(size_t)i * 4] = o;
}

// ---------------- transpose-cast: in [K][N] f32 -> out [N][K] bf16 ----------------
__global__ __launch_bounds__(256) void transpose_cast_kernel(const float* __restrict__ in,
                                                             ushort_t* __restrict__ out,
                                                             int K, int N) {
  __shared__ ushort_t t[64][65];
  const int bk = blockIdx.y * 64, bn = blockIdx.x * 64;
  const int tid = threadIdx.x;
#pragma unroll
  for (int i = 0; i < 4; i++) {
    int idx = i * 256 + tid;
    int r = idx >> 4, c4 = idx & 15;
    float4 v = *(const float4*)&in[(size_t)(bk + r) * N + bn + c4 * 4];
    t[c4 * 4 + 0][r] = f2bf(v.x);
    t[c4 * 4 + 1][r] = f2bf(v.y);
    t[c4 * 4 + 2][r] = f2bf(v.z);
    t[c4 * 4 + 3][r] = f2bf(v.w);
  }
  __syncthreads();
#pragma unroll
  for (int i = 0; i < 4; i++) {
    int idx = i * 256 + tid;
    int r = idx >> 4, c4 = idx & 15;
    ushort4 o;
    o.x = t[r][c4 * 4 + 0]; o.y = t[r][c4 * 4 + 1];
    o.z = t[r][c4 * 4 + 2]; o.w = t[r][c4 * 4 + 3];
    *(ushort4*)&out[(size_t)(bn + r) * K + bk + c4 * 4] = o;
  }
}

// ---------------- fused QKV weight transpose-cast into wT[4608][3584] ----------------
__global__ __launch_bounds__(256) void transpose_cast_qkv(
    const float* __restrict__ wq, const float* __restrict__ wk,
    const float* __restrict__ wv, ushort_t* __restrict__ out) {
  __shared__ ushort_t t[64][65];
  const int xb = blockIdx.x;           // n-tile in fused [0,72)
  const int bk = blockIdx.y * 64;
  const int tid = threadIdx.x;
  const float* src; int srcN, bnl;
  if (xb < 56) { src = wq; srcN = NH * HD; bnl = xb * 64; }
  else if (xb < 64) { src = wk; srcN = NKV * HD; bnl = (xb - 56) * 64; }
  else { src = wv; srcN = NKV * HD; bnl = (xb - 64) * 64; }
#pragma unroll
  for (int i = 0; i < 4; i++) {
    int idx = i * 256 + tid;
    int r = idx >> 4, c4 = idx & 15;
    float4 v = *(const float4*)&src[(size_t)(bk + r) * srcN + bnl + c4 * 4];
    t[c4 * 4 + 0][r] = f2bf(v.x);
    t[c4 * 4 + 1][r] = f2bf(v.y);
    t[c4 * 4 + 2][r] = f2bf(v.z);
    t[c4 * 4 + 3][r] = f2bf(v.w);
  }
  __syncthreads();
#pragma unroll
  for (int i = 0; i < 4; i++) {
    int idx = i * 256 + tid;
    int r = idx >> 4, c4 = idx & 15;
    ushort4 o;
    o.x = t[r][c4 * 4 + 0]; o.y = t[r][c4 * 4 + 1];
    o.z = t[r][c4 * 4 + 2]; o.w = t[r][c4 * 4 + 3];
    *(ushort4*)&out[(size_t)(xb * 64 + r) * HID + bk + c4 * 4] = o;
  }
}

// ---------------- bf16 MFMA GEMM: 128x128 tile, BK=32, 8 waves x half-work ----
// (Best measured: ~104 us/dispatch.) 8 waves of acc[2][4]: 18 waves/CU hide the
// 2-phase stage+barrier latency via TLP. 0 bank conflicts via ^((row>>1)&3).
__global__ __launch_bounds__(512) void gemm_mfma(
    const ushort_t* __restrict__ A, const ushort_t* __restrict__ BT,
    const float* __restrict__ bias, float* __restrict__ Cf, ushort_t* __restrict__ Cb,
    ushort_t* __restrict__ Ck, ushort_t* __restrict__ Cv,
    const float* __restrict__ bias_k, const float* __restrict__ bias_v,
    int M, int N, int K, int mode) {
  __shared__ __align__(16) ushort_t As[2][128 * 32];
  __shared__ __align__(16) ushort_t Bs[2][128 * 32];
  const int tid = threadIdx.x;
  const int w = tid >> 6, lane = tid & 63;
  const int g = lane >> 4, r16 = lane & 15;
  const int wr = w >> 1, wc = w & 1;    // 4 x 2 wave grid; wave tile 32x64
  const int swzr = (r16 >> 1) & 3;      // fragment-read granule swizzle

  // XCD-chunked bijective swizzle (m204): B-panel resident per XCD L2
  const int nwg = gridDim.x;
  const int ny = M >> 7;
  const int qq = nwg >> 3, rr = nwg & 7;
  const int xcd = blockIdx.x & 7, jj = blockIdx.x >> 3;
  const int wgid = (xcd < rr ? xcd * (qq + 1) : rr * (qq + 1) + (xcd - rr) * qq) + jj;
  const int bn = (wgid / ny) * 128;
  const int bm = (wgid % ny) * 128;

  f32x4 acc[2][4];
#pragma unroll
  for (int i = 0; i < 2; i++)
#pragma unroll
    for (int j2 = 0; j2 < 4; j2++) acc[i][j2] = (f32x4){0.f, 0.f, 0.f, 0.f};

  const int nk = K >> 5;  // 112

#define GSTAGE(BUF, T_)                                                                 \
  do {                                                                                  \
    const int k0_ = (T_) << 5;                                                          \
    int gi = tid;                                                                       \
    int row = gi >> 2, gc = gi & 3;                                                     \
    int gsrc = gc ^ ((row >> 1) & 3);                                                   \
    gload16(&A[(size_t)(bm + row) * K + k0_ + gsrc * 8], &As[BUF][gi * 8]);             \
    gload16(&BT[(size_t)(bn + row) * K + k0_ + gsrc * 8], &Bs[BUF][gi * 8]);            \
  } while (0)

  GSTAGE(0, 0);
  __syncthreads();

  int buf = 0;
  for (int t = 0; t < nk; t++) {
    if (t + 1 < nk) GSTAGE(buf ^ 1, t + 1);
    short8 af[2], bfr[4];
#pragma unroll
    for (int mi = 0; mi < 2; mi++)
      af[mi] = *(const short8*)&As[buf][((wr * 32 + mi * 16 + r16) * 4 + (g ^ swzr)) * 8];
#pragma unroll
    for (int ni = 0; ni < 4; ni++)
      bfr[ni] = *(const short8*)&Bs[buf][((wc * 64 + ni * 16 + r16) * 4 + (g ^ swzr)) * 8];
    __builtin_amdgcn_s_setprio(1);
#pragma unroll
    for (int mi = 0; mi < 2; mi++)
#pragma unroll
      for (int ni = 0; ni < 4; ni++)
        acc[mi][ni] = __builtin_amdgcn_mfma_f32_16x16x32_bf16(af[mi], bfr[ni], acc[mi][ni], 0, 0, 0);
    __builtin_amdgcn_s_setprio(0);
    __syncthreads();
    buf ^= 1;
  }
#undef GSTAGE

  if (mode == 3) {
#pragma unroll
    for (int mi = 0; mi < 2; mi++)
#pragma unroll
      for (int ni = 0; ni < 4; ni++)
#pragma unroll
        for (int r = 0; r < 4; r++) {
          int row = bm + wr * 32 + mi * 16 + 4 * g + r;
          int col = bn + wc * 64 + ni * 16 + r16;
          float v = acc[mi][ni][r];
          if (bn < NH * HD) {
            Cb[(size_t)row * (NH * HD) + col] = f2bf(v + bias[col]);
          } else if (bn < NH * HD + NKV * HD) {
            int c = col - NH * HD;
            Ck[(size_t)row * (NKV * HD) + c] = f2bf(v + bias_k[c]);
          } else {
            int c = col - (NH * HD + NKV * HD);
            Cv[(size_t)c * M + row] = f2bf(v + bias_v[c]);
          }
        }
    return;
  }
#pragma unroll
  for (int mi = 0; mi < 2; mi++)
#pragma unroll
    for (int ni = 0; ni < 4; ni++)
#pragma unroll
      for (int r = 0; r < 4; r++) {
        int row = bm + wr * 32 + mi * 16 + 4 * g + r;
        int col = bn + wc * 64 + ni * 16 + r16;
        float v = acc[mi][ni][r];
        if (bias) v += bias[col];
        if (mode == 0) Cf[(size_t)row * N + col] = v;
        else Cb[(size_t)row * N + col] = f2bf(v);
      }
}

// ---------------- fused RoPE on q[S][NH][128] + k[S][NKV][128] (bf16, vectorized) ----
__global__ __launch_bounds__(256) void rope_fused(
    ushort_t* __restrict__ q, ushort_t* __restrict__ k,
    const float* __restrict__ cosd, const float* __restrict__ sind) {
  const int s = blockIdx.x;
  const int t = threadIdx.x;
  const int hg = t >> 3;        // 0..31: 0-27 q heads, 28-31 k heads
  const int d0 = (t & 7) * 8;   // 0..56
  ushort_t* p = (hg < NH) ? q + ((size_t)s * NH + hg) * HD
                          : k + ((size_t)s * NKV + (hg - NH)) * HD;
  short8 a = *(short8*)(p + d0);
  short8 b = *(short8*)(p + d0 + 64);
  float4 c0 = *(const float4*)&cosd[s * 64 + d0];
  float4 c1 = *(const float4*)&cosd[s * 64 + d0 + 4];
  float4 s0 = *(const float4*)&sind[s * 64 + d0];
  float4 s1 = *(const float4*)&sind[s * 64 + d0 + 4];
  float cs[8] = {c0.x, c0.y, c0.z, c0.w, c1.x, c1.y, c1.z, c1.w};
  float sn[8] = {s0.x, s0.y, s0.z, s0.w, s1.x, s1.y, s1.z, s1.w};
  short8 ra, rb;
#pragma unroll
  for (int j = 0; j < 8; j++) {
    float x1 = bf2f((ushort_t)a[j]), x2 = bf2f((ushort_t)b[j]);
    ra[j] = (short)f2bf(x1 * cs[j] - x2 * sn[j]);
    rb[j] = (short)f2bf(x1 * sn[j] + x2 * cs[j]);
  }
  *(short8*)(p + d0) = ra;
  *(short8*)(p + d0 + 64) = rb;
}

// ---------------- split-K 32x32 swapped-operand causal GQA flash attention ----
// 1D grid 952; xcd = id&7; each XCD pair owns one kv-head (K+V = 4MB fits
// per-XCD L2). K AND V staged in LDS (dbuf, granule swizzle) - best measured.
// P packed with HW v_cvt_pk_bf16_f32; 4-chain max reduce.
__global__ __launch_bounds__(256) void attn_split(
    const ushort_t* __restrict__ q, const ushort_t* __restrict__ k,
    const ushort_t* __restrict__ vT, ushort_t* __restrict__ Opart,
    float* __restrict__ Mpart, float* __restrict__ Lpart) {
  const int i = blockIdx.x;          // 0..951
  const int xcd = i & 7, idx = i >> 3;
  const int kvh_ = xcd >> 1;
  const int j = idx * 2 + (xcd & 1); // 0..237 = 7 heads x 34 slots
  const int h = kvh_ * 7 + j / NSLOT;
  const int slotIdx = j % NSLOT;
  const int qt = SLOT_QT[slotIdx];
  const int c = SLOT_C[slotIdx], C = QT_NC[qt];
  const int T = 2 * qt + 2;
  const int tstart = (T * c) / C;
  const int tend = (T * (c + 1)) / C;
  const size_t slot = (size_t)h * NSLOT + slotIdx;
  const int kvh = h / GQA;
  const int q0 = qt * 128;
  const int tid = threadIdx.x, w = tid >> 6, lane = tid & 63;
  const int l31 = lane & 31, hi = lane >> 5;

  __shared__ __align__(16) ushort_t Ks[2][64 * 128];  // [key][d], granule ^= key&15
  __shared__ __align__(16) ushort_t Vs[2][128 * 64];  // [d][key], granule ^= d&7

  short8 qf[8];
  {
    const ushort_t* qp = q + (size_t)(q0 + w * 32 + l31) * (NH * HD) + h * HD + 8 * hi;
#pragma unroll
    for (int f = 0; f < 8; f++) qf[f] = *(const short8*)(qp + 16 * f);
  }
  float mrow = -1e30f, lrow = 0.f;
  f32x16 oa[4];
#pragma unroll
  for (int d = 0; d < 4; d++)
#pragma unroll
    for (int e = 0; e < 16; e++) oa[d][e] = 0.f;

#define STAGE(BUF, T_)                                                                  \
  do {                                                                                  \
    const int kb_ = (T_) * 64;                                                          \
    _Pragma("unroll") for (int i2 = 0; i2 < 4; i2++) {                                  \
      int gi = i2 * 256 + tid;                                                          \
      int key = gi >> 4, gd = gi & 15;                                                  \
      int gsrc = gd ^ (key & 15);                                                       \
      gload16(&k[(size_t)(kb_ + key) * (NKV * HD) + kvh * HD + gsrc * 8],               \
              &Ks[BUF][gi * 8]);                                                        \
    }                                                                                   \
    _Pragma("unroll") for (int i2 = 0; i2 < 4; i2++) {                                  \
      int gi = i2 * 256 + tid;                                                          \
      int drow = gi >> 3, gc = gi & 7;                                                  \
      int gsrc = gc ^ (drow & 7);                                                       \
      gload16(&vT[(size_t)(kvh * HD + drow) * SEQ + kb_ + gsrc * 8],                    \
              &Vs[BUF][gi * 8]);                                                        \
    }                                                                                   \
  } while (0)

  STAGE(0, tstart);
  __syncthreads();

  for (int t = tstart; t < tend; t++) {
    const int cur = (t - tstart) & 1;
    const int kb = t * 64;
    if (t + 1 < tend) STAGE(cur ^ 1, t + 1);

    const int qwave = q0 + w * 32;
    if (kb <= qwave + 31) {
      // ---- QK^T ----
      f32x16 sfr[2];
      __builtin_amdgcn_s_setprio(1);
#pragma unroll
      for (int st = 0; st < 2; st++) {
        f32x16 acc;
#pragma unroll
        for (int e = 0; e < 16; e++) acc[e] = 0.f;
        const int key = st * 32 + l31;
#pragma unroll
        for (int f = 0; f < 8; f++) {
          short8 kf = *(const short8*)&Ks[cur][(key * 16 + ((2 * f + hi) ^ (key & 15))) * 8];
          acc = __builtin_amdgcn_mfma_f32_32x32x16_bf16(kf, qf[f], acc, 0, 0, 0);
        }
        sfr[st] = acc;
      }
      __builtin_amdgcn_s_setprio(0);

      // ---- causal mask ----
      const int qg = q0 + w * 32 + l31;
      if (kb + 63 > qwave) {
#pragma unroll
        for (int st = 0; st < 2; st++)
#pragma unroll
          for (int e = 0; e < 16; e++) {
            int keyg = kb + st * 32 + (e & 3) + 8 * (e >> 2) + 4 * hi;
            if (keyg > qg) sfr[st][e] = -1e30f;
          }
      }

      // ---- per-lane online softmax (defer-max); 4-chain max reduce ----
      float pmv0 = -1e30f, pmv1 = -1e30f, pmv2 = -1e30f, pmv3 = -1e30f;
#pragma unroll
      for (int st = 0; st < 2; st++)
#pragma unroll
        for (int e = 0; e < 16; e += 4) {
          pmv0 = fmaxf(pmv0, sfr[st][e]);
          pmv1 = fmaxf(pmv1, sfr[st][e + 1]);
          pmv2 = fmaxf(pmv2, sfr[st][e + 2]);
          pmv3 = fmaxf(pmv3, sfr[st][e + 3]);
        }
      float pm = fmaxf(fmaxf(pmv0, pmv1), fmaxf(pmv2, pmv3));
      if (__any(pm > mrow + DTHR)) {
        float xm = fmaxf(pm, __shfl_xor(pm, 32));
        float nm = fmaxf(mrow, xm);
        float resc = exp2f((mrow - nm) * KS2);
        mrow = nm;
        lrow *= resc;
        float rr2[16];
#pragma unroll
        for (int r = 0; r < 16; r++) {
          int srcl = (r & 3) + 8 * (r >> 2) + 4 * hi;
          rr2[r] = __shfl(resc, srcl);
        }
#pragma unroll
        for (int d = 0; d < 4; d++)
#pragma unroll
          for (int r = 0; r < 16; r++) oa[d][r] *= rr2[r];
      }
      u32 pk[2][8];
      float psum = 0.f;
#pragma unroll
      for (int st = 0; st < 2; st++)
#pragma unroll
        for (int j2 = 0; j2 < 8; j2++) {
          float pa = exp2f((sfr[st][2 * j2] - mrow) * KS2);
          float pb = exp2f((sfr[st][2 * j2 + 1] - mrow) * KS2);
          psum += pa + pb;
          pk[st][j2] = cvtpk(pa, pb);
        }
      lrow += psum;

      // ---- build P A-frags via shfl_xor(32) ----
      short8 paf[4];
#pragma unroll
      for (int st = 0; st < 2; st++) {
        u32 x0 = (u32)__shfl_xor((int)pk[st][0], 32);
        u32 x1 = (u32)__shfl_xor((int)pk[st][1], 32);
        u32 x2 = (u32)__shfl_xor((int)pk[st][2], 32);
        u32 x3 = (u32)__shfl_xor((int)pk[st][3], 32);
        u32 x4 = (u32)__shfl_xor((int)pk[st][4], 32);
        u32 x5 = (u32)__shfl_xor((int)pk[st][5], 32);
        u32 x6 = (u32)__shfl_xor((int)pk[st][6], 32);
        u32 x7 = (u32)__shfl_xor((int)pk[st][7], 32);
        union { u32 wd[4]; short8 v; } fe, fo;
        if (hi == 0) {
          fe.wd[0] = pk[st][0]; fe.wd[1] = pk[st][1]; fe.wd[2] = x0; fe.wd[3] = x1;
          fo.wd[0] = pk[st][4]; fo.wd[1] = pk[st][5]; fo.wd[2] = x4; fo.wd[3] = x5;
        } else {
          fe.wd[0] = x2; fe.wd[1] = x3; fe.wd[2] = pk[st][2]; fe.wd[3] = pk[st][3];
          fo.wd[0] = x6; fo.wd[1] = x7; fo.wd[2] = pk[st][6]; fo.wd[3] = pk[st][7];
        }
        paf[2 * st] = fe.v;
        paf[2 * st + 1] = fo.v;
      }

      // ---- PV from LDS V (granule-swizzled) ----
#pragma unroll
      for (int half = 0; half < 2; half++) {
        short8 vf[8];
#pragma unroll
        for (int db = 0; db < 2; db++)
#pragma unroll
          for (int ks = 0; ks < 4; ks++) {
            int drow = (half * 2 + db) * 32 + l31;
            vf[db * 4 + ks] =
                *(const short8*)&Vs[cur][(drow * 8 + ((ks * 2 + hi) ^ (drow & 7))) * 8];
          }
        __builtin_amdgcn_s_setprio(1);
#pragma unroll
        for (int db = 0; db < 2; db++)
#pragma unroll
          for (int ks = 0; ks < 4; ks++)
            oa[half * 2 + db] = __builtin_amdgcn_mfma_f32_32x32x16_bf16(
                paf[ks], vf[db * 4 + ks], oa[half * 2 + db], 0, 0, 0);
        __builtin_amdgcn_s_setprio(0);
      }
    }
    __syncthreads();
  }
#undef STAGE

  // ---- epilogue ----
  lrow += __shfl_xor(lrow, 32);
#pragma unroll
  for (int d = 0; d < 4; d++)
#pragma unroll
    for (int r = 0; r < 16; r++) {
      int qloc = w * 32 + (r & 3) + 8 * (r >> 2) + 4 * hi;
      Opart[(slot * 128 + qloc) * 128 + d * 32 + l31] = f2bf(oa[d][r]);
    }
  if (hi == 0) {
    Mpart[slot * 128 + w * 32 + l31] = mrow;
    Lpart[slot * 128 + w * 32 + l31] = lrow;
  }
}

// ---------------- combine split-K partials (vectorized: ushort4, 2 units/thread) ----
__global__ __launch_bounds__(448) void attn_reduce(
    const ushort_t* __restrict__ Opart, const float* __restrict__ Mpart,
    const float* __restrict__ Lpart, ushort_t* __restrict__ out) {
  const int s = blockIdx.x;
  const int qt = s >> 7, lr = s & 127;
  const int C = QT_NC[qt];
#pragma unroll
  for (int u = threadIdx.x; u < 896; u += 448) {
    const int h = u >> 5;         // 0..27
    const int d4 = (u & 31) * 4;  // 0..124
    float Mv[4];
    float M = -1e30f;
    for (int c = 0; c < C; c++) {
      int sl = RED_SLOT[RED_BASE[qt] + c];
      Mv[c] = Mpart[((size_t)h * NSLOT + sl) * 128 + lr];
      M = fmaxf(M, Mv[c]);
    }
    float L = 0.f, O0 = 0.f, O1 = 0.f, O2 = 0.f, O3 = 0.f;
    for (int c = 0; c < C; c++) {
      int sl = RED_SLOT[RED_BASE[qt] + c];
      size_t base = ((size_t)h * NSLOT + sl) * 128 + lr;
      float wgt = exp2f((Mv[c] - M) * KS2);
      L += wgt * Lpart[base];
      ushort4 o4 = *(const ushort4*)&Opart[base * 128 + d4];
      O0 += wgt * bf2f(o4.x); O1 += wgt * bf2f(o4.y);
      O2 += wgt * bf2f(o4.z); O3 += wgt * bf2f(o4.w);
    }
    const float inv = 1.f / L;
    ushort4 r;
    r.x = f2bf(O0 * inv); r.y = f2bf(O1 * inv);
    r.z = f2bf(O2 * inv); r.w = f2bf(O3 * inv);
    *(ushort4*)&out[(size_t)s * (NH * HD) + h * HD + d4] = r;
  }
}

extern "C" void kernel_launch(void* const* d_in, const int* in_sizes, int n_in,
                              void* d_out, int out_size, void* d_ws, size_t ws_size,
                              hipStream_t stream) {
  const float* x    = (const float*)d_in[0];
  const float* wq   = (const float*)d_in[1];
  const float* bq   = (const float*)d_in[2];
  const float* wk   = (const float*)d_in[3];
  const float* bk   = (const float*)d_in[4];
  const float* wv   = (const float*)d_in[5];
  const float* bv   = (const float*)d_in[6];
  const float* wo   = (const float*)d_in[7];
  const float* cosd = (const float*)d_in[8];
  const float* sind = (const float*)d_in[9];
  float* out = (float*)d_out;

  ushort_t* ws   = (ushort_t*)d_ws;
  ushort_t* wT   = ws;                              // [4608][3584] qkv^T; later partials; later wo^T
  ushort_t* xb   = wT + (size_t)NQKV * HID;         // [2048][3584] (later attn out)
  ushort_t* qb   = xb + (size_t)SEQ * HID;          // [2048][3584]
  ushort_t* kb_  = qb + (size_t)SEQ * HID;          // [2048][512]
  ushort_t* vbT  = kb_ + (size_t)SEQ * (NKV * HD);  // [512][2048]
  ushort_t* aob  = xb;                              // reuse after QKV GEMM

  // split-K partials overlay the (dead after QKV GEMM) wT region:
  // 28*34*128*128*2B = 31.2MB + 2*28*34*128*4B = 0.98MB <= 33.0MB
  ushort_t* Opart = wT;                                            // [28][34][128][128] bf16
  float* Mpart = (float*)(wT + (size_t)NH * NSLOT * 128 * 128);    // [28][34][128]
  float* Lpart = Mpart + (size_t)NH * NSLOT * 128;                 // [28][34][128]

  // 1. cast x -> bf16
  cast_bf16_kernel<<<(SEQ * HID / 4) / 256, 256, 0, stream>>>(x, xb, SEQ * HID / 4);
  // 2. fused transpose-cast of wq/wk/wv into [4608][3584]
  transpose_cast_qkv<<<dim3(NQKV / 64, HID / 64), 256, 0, stream>>>(wq, wk, wv, wT);
  // 3. fused QKV projection (128^2 tiles, 8 waves, 1D grid, XCD-chunked)
  gemm_mfma<<<dim3((NQKV / 128) * (SEQ / 128)), 512, 0, stream>>>(
      xb, wT, bq, nullptr, qb, kb_, vbT, bk, bv, SEQ, NQKV, HID, 3);
  // 4. fused RoPE on q and k (vectorized)
  rope_fused<<<dim3(SEQ), 256, 0, stream>>>(qb, kb_, cosd, sind);
  // 5. split-K attention (XCD-pinned 1D grid) + reduce
  attn_split<<<dim3(8 * 119), 256, 0, stream>>>(qb, kb_, vbT, Opart, Mpart, Lpart);
  attn_reduce<<<dim3(SEQ), 448, 0, stream>>>(Opart, Mpart, Lpart, aob);
  // 6. output projection (reuse wT region for wo^T; partials dead after reduce)
  transpose_cast_kernel<<<dim3(HID / 64, HID / 64), 256, 0, stream>>>(wo, wT, HID, HID);
  gemm_mfma<<<dim3((HID / 128) * (SEQ / 128)), 512, 0, stream>>>(
      aob, wT, nullptr, out, nullptr, nullptr, nullptr, nullptr, nullptr, SEQ, HID, HID, 0);
}